// Round 16
// baseline (86.828 us; speedup 1.0000x reference)
//
#include <hip/hip_runtime.h>
#include <hip/hip_bf16.h>
#include <cstdint>

// x: [8,8192,512] f32 -> LN over E=512 -> A=[16384,2048] (row-major flatten)
// W: [2048,512] f32, b: [512]; out = gelu(A @ W' + b').
// NO h buffer: gemm stages RAW f32 x (pure-DMA gload_lds), casts to bf16 at
// frag-read, and folds the LN affine into tok-boundary rescales + epilogue:
//   out[m,n] = sum_tok rs[m,tok]*P_tok + sum_tok nm[m,tok]*S_tok[n] + b'[n]
//   (P_tok = partial x@W' over k in tok*512..+512; S_tok = colsum of gammaW)
#define XROWS   65536
#define E       512
#define MROWS   16384
#define KDIM    2048
#define NDIM    512
#define NT      32        // K-steps of 64

typedef __attribute__((ext_vector_type(4))) float f32x4;
typedef __attribute__((ext_vector_type(2))) float f32x2;
typedef __attribute__((ext_vector_type(8))) unsigned short u16x8;
typedef __attribute__((ext_vector_type(8))) __bf16 bf16x8;

__device__ __forceinline__ unsigned short f2bf(float f) {
  unsigned u = __builtin_bit_cast(unsigned, f);
  u += 0x7FFFu + ((u >> 16) & 1u);   // round-to-nearest-even
  return (unsigned short)(u >> 16);
}

typedef const __attribute__((address_space(1))) unsigned char ga_u8;
typedef __attribute__((address_space(3))) unsigned char ls_u8;
__device__ __forceinline__ void gload16(const void* g, void* l) {
  __builtin_amdgcn_global_load_lds((ga_u8*)g, (ls_u8*)l, 16, 0, 0);
}

// fast gelu (tanh form), |err vs erf form| <= ~3e-3 << 0.094 threshold
__device__ __forceinline__ float gelu_f(float v) {
  float p = v * (2.3022083f + 0.1029432f * (v * v));
  p = fminf(p, 80.0f);
  const float Ee = exp2f(p);
  return v * Ee * __builtin_amdgcn_rcpf(Ee + 1.0f);
}

// ---------------------------------------------------------------------------
// Setup: blocks 0..255 WT transpose+gamma-fold; 256..287 beta partials;
// 288..319 gamma partials (for S_tok colsums).
//   WT[n][k] = bf16(gamma[k%512] * W[k][n])
// ---------------------------------------------------------------------------
__global__ __launch_bounds__(256) void setup_kernel(const float* __restrict__ W,
                                                    const float* __restrict__ gamma,
                                                    const float* __restrict__ beta,
                                                    unsigned short* __restrict__ WT,
                                                    float* __restrict__ partial,
                                                    float* __restrict__ partial2) {
  __shared__ float tile[64][68];
  const int t = threadIdx.x;
  if (blockIdx.x >= 256) {           // weighted column partials
    const int idx = blockIdx.x - 256;          // 0..63
    const int bk = idx & 31;
    const float* wv = (idx < 32) ? beta : gamma;
    float* dst = (idx < 32) ? partial : partial2;
    float a0 = 0.f, a1 = 0.f;
    for (int k = 0; k < 64; ++k) {
      const int kg = bk * 64 + k;
      const float be = wv[kg & (E - 1)];
      a0 += be * W[(size_t)kg * NDIM + t];
      a1 += be * W[(size_t)kg * NDIM + 256 + t];
    }
    dst[bk * NDIM + t] = a0;
    dst[bk * NDIM + 256 + t] = a1;
    return;
  }
  const int bk = blockIdx.x >> 3;
  const int bn = blockIdx.x & 7;
  const int c4 = (t & 15) * 4;
#pragma unroll
  for (int i = 0; i < 4; ++i) {
    const int r = (t >> 4) + i * 16;
    const f32x4 v = *(const f32x4*)&W[(size_t)(bk * 64 + r) * NDIM + bn * 64 + c4];
    tile[r][c4 + 0] = v.x; tile[r][c4 + 1] = v.y;
    tile[r][c4 + 2] = v.z; tile[r][c4 + 3] = v.w;
  }
  __syncthreads();
#pragma unroll
  for (int j = 0; j < 2; ++j) {
    const int n  = j * 32 + (t >> 3);
    const int kb = (t & 7) * 8;
    const int kg0 = (bk & 7) * 64 + kb;
    const f32x4 g0 = *(const f32x4*)(gamma + kg0);
    const f32x4 g1 = *(const f32x4*)(gamma + kg0 + 4);
    const float gg[8] = {g0.x, g0.y, g0.z, g0.w, g1.x, g1.y, g1.z, g1.w};
    u16x8 o;
#pragma unroll
    for (int q = 0; q < 8; ++q) o[q] = f2bf(gg[q] * tile[kb + q][n]);
    *(u16x8*)&WT[(size_t)(bn * 64 + n) * KDIM + bk * 64 + kb] = o;
  }
}

// reduce: biasf[c] = b[c] + sum beta-partials; colS[tok*512+c] = per-tok
// gamma-partial sums (8 bk-blocks per tok).
__global__ __launch_bounds__(256) void kbias2(const float* __restrict__ b,
                                              const float* __restrict__ partial,
                                              const float* __restrict__ partial2,
                                              float* __restrict__ biasf,
                                              float* __restrict__ colS) {
  const int c = blockIdx.x * 256 + threadIdx.x;   // grid 2 x 256
  float s = b[c];
#pragma unroll 4
  for (int j = 0; j < 32; ++j) s += partial[j * NDIM + c];
  biasf[c] = s;
#pragma unroll
  for (int tok = 0; tok < 4; ++tok) {
    float g = 0.f;
#pragma unroll
    for (int j = 0; j < 8; ++j) g += partial2[(tok * 8 + j) * NDIM + c];
    colS[tok * NDIM + c] = g;
  }
}

// ---------------------------------------------------------------------------
// Stats: one wave per TWO x-rows -> (rs, nm) = (rstd, -mean*rstd) per row.
// ---------------------------------------------------------------------------
__global__ __launch_bounds__(256, 4) void stats_kernel(const float* __restrict__ x,
                                                       f32x2* __restrict__ stats) {
  const int w = threadIdx.x >> 6, l = threadIdx.x & 63;
  const size_t row = (size_t)blockIdx.x * 8 + w * 2;
  const float* xr = x + row * E + l * 8;
  const f32x4 a0 = *(const f32x4*)xr;
  const f32x4 a1 = *(const f32x4*)(xr + 4);
  const f32x4 b0 = *(const f32x4*)(xr + E);
  const f32x4 b1 = *(const f32x4*)(xr + E + 4);
  float av[8] = {a0.x, a0.y, a0.z, a0.w, a1.x, a1.y, a1.z, a1.w};
  float bv[8] = {b0.x, b0.y, b0.z, b0.w, b1.x, b1.y, b1.z, b1.w};
  float s0 = 0.f, q0 = 0.f, s1 = 0.f, q1 = 0.f;
#pragma unroll
  for (int j = 0; j < 8; ++j) {
    s0 += av[j]; q0 += av[j] * av[j];
    s1 += bv[j]; q1 += bv[j] * bv[j];
  }
#pragma unroll
  for (int off = 32; off > 0; off >>= 1) {
    s0 += __shfl_xor(s0, off); q0 += __shfl_xor(q0, off);
    s1 += __shfl_xor(s1, off); q1 += __shfl_xor(q1, off);
  }
  if (l == 0) {
    const float m0 = s0 * (1.0f / E);
    const float r0 = rsqrtf(q0 * (1.0f / E) - m0 * m0 + 1e-6f);
    const float m1 = s1 * (1.0f / E);
    const float r1 = rsqrtf(q1 * (1.0f / E) - m1 * m1 + 1e-6f);
    f32x2 o0; o0.x = r0; o0.y = -m0 * r0;
    f32x2 o1; o1.x = r1; o1.y = -m1 * r1;
    stats[row] = o0;
    stats[row + 1] = o1;
  }
}

// ---------------------------------------------------------------------------
// Fused GEMM (champion loop shape, A = raw f32 x):
// 128x128 tile, BK=64, 4 waves (2x2), SINGLE buffer, 2 barriers/K-step.
// LDS 52KB: A f32 32K @0 (rows 256B, XOR-swz 16B units by row&7),
//           B bf16 16K @32768 (champion layout), stats panel 4K @49152.
// A frag: 2x ds_read_b128 f32 -> (__bf16) cvt in-reg (LN folded OUT of loop).
// Tok-boundary rescale (t=8,16,24): acc *= rs_prev/rs_cur per row.
// Epilogue: v = rs3*acc + sum_tok nm_tok*S_tok[col] + b'[col]; gelu.
// T1 XCD-chunked bijective swizzle (512 = 8x64).
// ---------------------------------------------------------------------------
__global__ __launch_bounds__(256, 2) void gemm_kernel(const float* __restrict__ x,
                                                      const f32x2* __restrict__ stats,
                                                      const unsigned short* __restrict__ Bt,
                                                      const float* __restrict__ biasf,
                                                      const float* __restrict__ colS,
                                                      float* __restrict__ out) {
  __shared__ char smem[53248];
  const int tid = threadIdx.x;
  const int l = tid & 63, w = tid >> 6;
  const int l7 = l & 7, l15 = l & 15, lhi = l >> 4;
  const int wr = w >> 1, wc = w & 1;

  // XCD chunking: grid 512 = 8 XCDs x 64; bn in low 2 bits of wg
  const int wg = ((blockIdx.x & 7) << 6) | (blockIdx.x >> 3);
  const int bn = wg & 3;
  const int bm = wg >> 2;
  const size_t arow0 = (size_t)bm * 128;
  const int    brow0 = bn * 128;

  // A staging (f32): call i: row = i*16 + (tid>>4), 16B unit u = tid&15 of
  // the 256B K-window; source pre-swizzled (u*16)^((row&7)<<4); dest linear.
  const int ar = tid >> 4;
  const int aswz = ((tid & 15) * 16) ^ ((ar & 7) << 4);
  const char* gX = (const char*)x + ((size_t)(arow0 + ar) * KDIM) * 4 + aswz;
  // B staging (champion): rows i*32 + w*8 + l/8, swizzled source col
  const int srow = w * 8 + (l >> 3);
  const int swzB = (l7 * 16) ^ ((l >> 3) << 4);
  const char* gB = (const char*)Bt + ((size_t)(brow0 + srow) * KDIM) * 2 + swzB;

  f32x4 acc[4][4];
#pragma unroll
  for (int m = 0; m < 4; ++m)
#pragma unroll
    for (int n = 0; n < 4; ++n) acc[m][n] = (f32x4){0.f, 0.f, 0.f, 0.f};

  const int csB = (lhi * 16) ^ (l7 * 16);   // B frag swizzled byte col

  // stats panel (128 A-rows x 4 toks x 8B = 4KB, contiguous in global):
  gload16((const char*)stats + arow0 * 32 + tid * 16, smem + 49152 + tid * 16);
#define PAN(rowL, tok) (*(const f32x2*)(smem + 49152 + ((rowL) * 4 + (tok)) * 8))

  for (int t = 0; t < NT; ++t) {
    // tok-boundary rescale: acc currently in rs[tok-1] units -> rs[tok]
    if (t == 8 || t == 16 || t == 24) {
      const int tk = t >> 3;
#pragma unroll
      for (int m = 0; m < 4; ++m)
#pragma unroll
        for (int r = 0; r < 4; ++r) {
          const int rowL = wr * 64 + m * 16 + lhi * 4 + r;
          const float ratio = PAN(rowL, tk - 1).x *
                              __builtin_amdgcn_rcpf(PAN(rowL, tk).x);
#pragma unroll
          for (int n = 0; n < 4; ++n) acc[m][n][r] *= ratio;
        }
    }
    __syncthreads();               // all waves done reading buffer
    {
      const char* px = gX + (size_t)t * 256;
#pragma unroll
      for (int i = 0; i < 8; ++i)  // A: 32KB f32
        gload16(px + (size_t)i * 16 * KDIM * 4, smem + i * 4096 + tid * 16);
      const char* pb = gB + (size_t)t * 128;
#pragma unroll
      for (int i = 0; i < 4; ++i)  // B: 16KB bf16
        gload16(pb + (size_t)i * 32 * KDIM * 2, smem + 32768 + (i * 32 + w * 8) * 128);
    }
    __syncthreads();               // drains vmcnt: staged data visible
#pragma unroll
    for (int kk = 0; kk < 2; ++kk) {
      bf16x8 avv[4], bv[4];
#pragma unroll
      for (int m = 0; m < 4; ++m) {
        const int row = wr * 64 + m * 16 + l15;
        const char* ap = smem + row * 256 + kk * 128;
        const f32x4 lo = *(const f32x4*)(ap + ((((lhi * 2 + 0) ^ l7)) << 4));
        const f32x4 hi = *(const f32x4*)(ap + ((((lhi * 2 + 1) ^ l7)) << 4));
        bf16x8 o;
        o[0] = (__bf16)lo.x; o[1] = (__bf16)lo.y;
        o[2] = (__bf16)lo.z; o[3] = (__bf16)lo.w;
        o[4] = (__bf16)hi.x; o[5] = (__bf16)hi.y;
        o[6] = (__bf16)hi.z; o[7] = (__bf16)hi.w;
        avv[m] = o;
      }
#pragma unroll
      for (int n = 0; n < 4; ++n)
        bv[n] = *(const bf16x8*)(smem + 32768 +
                                 (wc * 64 + n * 16 + l15) * 128 + (csB ^ (kk * 64)));
#pragma unroll
      for (int m = 0; m < 4; ++m)
#pragma unroll
        for (int n = 0; n < 4; ++n)
          acc[m][n] = __builtin_amdgcn_mfma_f32_16x16x32_bf16(avv[m], bv[n],
                                                              acc[m][n], 0, 0, 0);
    }
  }

  // epilogue: v = rs3*acc + sum_tok nm_tok*S_tok[col] + b'[col]; gelu.
  // C/D layout (m89): col = l&15, row = (l>>4)*4 + reg
  float S0[4], S1[4], S2[4], S3[4], BB[4];
#pragma unroll
  for (int n = 0; n < 4; ++n) {
    const int col = brow0 + wc * 64 + n * 16 + l15;
    BB[n] = biasf[col];
    S0[n] = colS[col];           S1[n] = colS[NDIM + col];
    S2[n] = colS[2 * NDIM + col]; S3[n] = colS[3 * NDIM + col];
  }
#pragma unroll
  for (int m = 0; m < 4; ++m)
#pragma unroll
    for (int r = 0; r < 4; ++r) {
      const int rowL = wr * 64 + m * 16 + lhi * 4 + r;
      const f32x2 p0 = PAN(rowL, 0), p1 = PAN(rowL, 1);
      const f32x2 p2 = PAN(rowL, 2), p3 = PAN(rowL, 3);
      const size_t grow = arow0 + rowL;
#pragma unroll
      for (int n = 0; n < 4; ++n) {
        const int col = brow0 + wc * 64 + n * 16 + l15;
        const float v = p3.x * acc[m][n][r]
                      + p0.y * S0[n] + p1.y * S1[n] + p2.y * S2[n] + p3.y * S3[n]
                      + BB[n];
        out[grow * NDIM + col] = gelu_f(v);
      }
    }
#undef PAN
}

// ---------------------------------------------------------------------------
extern "C" void kernel_launch(void* const* d_in, const int* in_sizes, int n_in,
                              void* d_out, int out_size, void* d_ws, size_t ws_size,
                              hipStream_t stream) {
  const float* x     = (const float*)d_in[0];
  const float* gamma = (const float*)d_in[1];
  const float* beta  = (const float*)d_in[2];
  const float* W     = (const float*)d_in[3];
  const float* b     = (const float*)d_in[4];
  float* out = (float*)d_out;

  // ws: WT 2MB | stats 512KB | partial 64KB | partial2 64KB | biasf 2KB | colS 8KB
  char* p = (char*)d_ws;
  unsigned short* WT = (unsigned short*)p;            p += (size_t)NDIM * KDIM * 2;
  f32x2* stats       = (f32x2*)p;                     p += (size_t)XROWS * 8;
  float* partial     = (float*)p;                     p += (size_t)32 * NDIM * 4;
  float* partial2    = (float*)p;                     p += (size_t)32 * NDIM * 4;
  float* biasf       = (float*)p;                     p += (size_t)NDIM * 4;
  float* colS        = (float*)p;

  setup_kernel<<<320, 256, 0, stream>>>(W, gamma, beta, WT, partial, partial2);
  kbias2<<<2, 256, 0, stream>>>(b, partial, partial2, biasf, colS);
  stats_kernel<<<XROWS / 8, 256, 0, stream>>>(x, stats);
  gemm_kernel<<<(MROWS / 128) * 4, 256, 0, stream>>>(x, stats, WT, biasf, colS, out);
}

// Round 17
// 79.980 us; speedup vs baseline: 1.0856x; 1.0856x over previous
//
#include <hip/hip_runtime.h>
#include <hip/hip_bf16.h>
#include <cstdint>

// x: [8,8192,512] f32 -> LN over E=512 -> h=[16384,2048] bf16 (row-major flatten)
// W: [2048,512] f32, b: [512]; out = gelu(h @ W' + b'),
// W' = gamma-folded W (bf16, transposed), b' = b + beta @ W.
// CHAMPION configuration (R10, 80.0 us): setup+kbias2 | ln 2-row/wave |
// gemm 128x128 single-buf gload_lds + T2 swizzle + XCD chunking.
#define XROWS   65536
#define E       512
#define MROWS   16384
#define KDIM    2048
#define NDIM    512
#define NT      32        // K-steps of 64

typedef __attribute__((ext_vector_type(4))) float f32x4;
typedef __attribute__((ext_vector_type(8))) unsigned short u16x8;
typedef __attribute__((ext_vector_type(8))) __bf16 bf16x8;

__device__ __forceinline__ unsigned short f2bf(float f) {
  unsigned u = __builtin_bit_cast(unsigned, f);
  u += 0x7FFFu + ((u >> 16) & 1u);   // round-to-nearest-even
  return (unsigned short)(u >> 16);
}

typedef const __attribute__((address_space(1))) unsigned char ga_u8;
typedef __attribute__((address_space(3))) unsigned char ls_u8;
__device__ __forceinline__ void gload16(const void* g, void* l) {
  __builtin_amdgcn_global_load_lds((ga_u8*)g, (ls_u8*)l, 16, 0, 0);
}

// fast gelu (tanh form), |err vs erf form| <= ~3e-3 << 0.094 threshold
__device__ __forceinline__ float gelu_f(float v) {
  float p = v * (2.3022083f + 0.1029432f * (v * v));
  p = fminf(p, 80.0f);
  const float Ee = exp2f(p);
  return v * Ee * __builtin_amdgcn_rcpf(Ee + 1.0f);
}

// ---------------------------------------------------------------------------
// Merged setup: blocks 0..255 -> WT transpose+gamma-fold; 256..287 -> beta
// partials.  WT[n][k] = bf16(gamma[k%512] * W[k][n])
// ---------------------------------------------------------------------------
__global__ __launch_bounds__(256) void setup_kernel(const float* __restrict__ W,
                                                    const float* __restrict__ gamma,
                                                    const float* __restrict__ beta,
                                                    unsigned short* __restrict__ WT,
                                                    float* __restrict__ partial) {
  __shared__ float tile[64][68];
  const int t = threadIdx.x;
  if (blockIdx.x >= 256) {           // beta-fold partials
    const int bk = blockIdx.x - 256;
    float a0 = 0.f, a1 = 0.f;
    for (int k = 0; k < 64; ++k) {
      const int kg = bk * 64 + k;
      const float be = beta[kg & (E - 1)];
      a0 += be * W[(size_t)kg * NDIM + t];
      a1 += be * W[(size_t)kg * NDIM + 256 + t];
    }
    partial[bk * NDIM + t] = a0;
    partial[bk * NDIM + 256 + t] = a1;
    return;
  }
  const int bk = blockIdx.x >> 3;
  const int bn = blockIdx.x & 7;
  const int c4 = (t & 15) * 4;
#pragma unroll
  for (int i = 0; i < 4; ++i) {
    const int r = (t >> 4) + i * 16;
    const f32x4 v = *(const f32x4*)&W[(size_t)(bk * 64 + r) * NDIM + bn * 64 + c4];
    tile[r][c4 + 0] = v.x; tile[r][c4 + 1] = v.y;
    tile[r][c4 + 2] = v.z; tile[r][c4 + 3] = v.w;
  }
  __syncthreads();
#pragma unroll
  for (int j = 0; j < 2; ++j) {
    const int n  = j * 32 + (t >> 3);
    const int kb = (t & 7) * 8;
    const int kg0 = (bk & 7) * 64 + kb;
    const f32x4 g0 = *(const f32x4*)(gamma + kg0);
    const f32x4 g1 = *(const f32x4*)(gamma + kg0 + 4);
    const float gg[8] = {g0.x, g0.y, g0.z, g0.w, g1.x, g1.y, g1.z, g1.w};
    u16x8 o;
#pragma unroll
    for (int q = 0; q < 8; ++q) o[q] = f2bf(gg[q] * tile[kb + q][n]);
    *(u16x8*)&WT[(size_t)(bn * 64 + n) * KDIM + bk * 64 + kb] = o;
  }
}

__global__ __launch_bounds__(256) void kbias2(const float* __restrict__ b,
                                              const float* __restrict__ partial,
                                              float* __restrict__ biasf) {
  const int c = blockIdx.x * 256 + threadIdx.x;
  float s = b[c];
  for (int j = 0; j < 32; ++j) s += partial[j * NDIM + c];
  biasf[c] = s;
}

// ---------------------------------------------------------------------------
// LayerNorm: one wave per TWO x-rows of 512 f32 -> bf16 h (at BW floor).
// ---------------------------------------------------------------------------
__global__ __launch_bounds__(256, 4) void ln_kernel(const float* __restrict__ x,
                                                    unsigned short* __restrict__ h) {
  const int w = threadIdx.x >> 6, l = threadIdx.x & 63;
  const size_t row = (size_t)blockIdx.x * 8 + w * 2;   // rows row, row+1
  const float* xr = x + row * E + l * 8;
  const f32x4 a0 = *(const f32x4*)xr;
  const f32x4 a1 = *(const f32x4*)(xr + 4);
  const f32x4 b0 = *(const f32x4*)(xr + E);
  const f32x4 b1 = *(const f32x4*)(xr + E + 4);
  float av[8] = {a0.x, a0.y, a0.z, a0.w, a1.x, a1.y, a1.z, a1.w};
  float bv[8] = {b0.x, b0.y, b0.z, b0.w, b1.x, b1.y, b1.z, b1.w};
  float s0 = 0.f, q0 = 0.f, s1 = 0.f, q1 = 0.f;
#pragma unroll
  for (int j = 0; j < 8; ++j) {
    s0 += av[j]; q0 += av[j] * av[j];
    s1 += bv[j]; q1 += bv[j] * bv[j];
  }
#pragma unroll
  for (int off = 32; off > 0; off >>= 1) {
    s0 += __shfl_xor(s0, off); q0 += __shfl_xor(q0, off);
    s1 += __shfl_xor(s1, off); q1 += __shfl_xor(q1, off);
  }
  const float mean0 = s0 * (1.0f / E);
  const float rstd0 = rsqrtf(q0 * (1.0f / E) - mean0 * mean0 + 1e-6f);
  const float nm0   = -mean0 * rstd0;
  const float mean1 = s1 * (1.0f / E);
  const float rstd1 = rsqrtf(q1 * (1.0f / E) - mean1 * mean1 + 1e-6f);
  const float nm1   = -mean1 * rstd1;
  u16x8 o0, o1;
#pragma unroll
  for (int j = 0; j < 8; ++j) {
    o0[j] = f2bf(av[j] * rstd0 + nm0);
    o1[j] = f2bf(bv[j] * rstd1 + nm1);
  }
  *(u16x8*)(h + row * E + l * 8) = o0;
  *(u16x8*)(h + (row + 1) * E + l * 8) = o1;
}

// ---------------------------------------------------------------------------
// GEMM champion: 128x128 tile, BK=64, 4 waves (2x2), SINGLE 32KB buffer,
// 2 barriers/K-step, gload_lds staging (linear dest + pre-swizzled source;
// T2 XOR on ds_read), __launch_bounds__(256,3).
// T1 XCD-chunked bijective swizzle (512 = 8x64): 4 bn-siblings per bm on one
// XCD -> h panel fetched once, L2-shared.
// ---------------------------------------------------------------------------
__global__ __launch_bounds__(256, 3) void gemm_kernel(const unsigned short* __restrict__ A,
                                                      const unsigned short* __restrict__ Bt,
                                                      const float* __restrict__ biasf,
                                                      float* __restrict__ out) {
  __shared__ char smem[32768];   // A 16KB @0, B 16KB @16384
  const int tid = threadIdx.x;
  const int l = tid & 63, w = tid >> 6;
  const int l7 = l & 7, l15 = l & 15, lhi = l >> 4;
  const int wr = w >> 1, wc = w & 1;

  // XCD chunking: grid 512 = 8 XCDs x 64; bn in low 2 bits of wg
  const int wg = ((blockIdx.x & 7) << 6) | (blockIdx.x >> 3);
  const int bn = wg & 3;
  const int bm = wg >> 2;
  const size_t arow0 = (size_t)bm * 128;
  const int    brow0 = bn * 128;

  // staging: thread covers rows {i*32 + w*8 + (l>>3)}, swizzled source col
  const int srow = w * 8 + (l >> 3);
  const int swz  = (l7 * 16) ^ ((l >> 3) << 4);
  const char* gA = (const char*)A  + ((size_t)(arow0 + srow) * KDIM) * 2 + swz;
  const char* gB = (const char*)Bt + ((size_t)(brow0 + srow) * KDIM) * 2 + swz;

  f32x4 acc[4][4];
#pragma unroll
  for (int m = 0; m < 4; ++m)
#pragma unroll
    for (int n = 0; n < 4; ++n) acc[m][n] = (f32x4){0.f, 0.f, 0.f, 0.f};

  // frag-read swizzled k-byte for kk=0; kk=1 flips bit 6 (outside swizzle)
  const int cs0 = (lhi * 16) ^ (l7 * 16);

  for (int t = 0; t < NT; ++t) {
    __syncthreads();               // all waves done reading buffer
    {
      const char* pa = gA + (size_t)t * 128;
      const char* pb = gB + (size_t)t * 128;
#pragma unroll
      for (int i = 0; i < 4; ++i) {
        gload16(pa + (size_t)i * 32 * KDIM * 2, smem + (i * 32 + w * 8) * 128);
        gload16(pb + (size_t)i * 32 * KDIM * 2, smem + 16384 + (i * 32 + w * 8) * 128);
      }
    }
    __syncthreads();               // drains vmcnt(0): staged data visible
#pragma unroll
    for (int kk = 0; kk < 2; ++kk) {
      const int co = cs0 ^ (kk * 64);
      bf16x8 av[4], bv[4];
#pragma unroll
      for (int m = 0; m < 4; ++m)
        av[m] = *(const bf16x8*)(smem + (wr * 64 + m * 16 + l15) * 128 + co);
#pragma unroll
      for (int n = 0; n < 4; ++n)
        bv[n] = *(const bf16x8*)(smem + 16384 + (wc * 64 + n * 16 + l15) * 128 + co);
#pragma unroll
      for (int m = 0; m < 4; ++m)
#pragma unroll
        for (int n = 0; n < 4; ++n)
          acc[m][n] = __builtin_amdgcn_mfma_f32_16x16x32_bf16(av[m], bv[n],
                                                              acc[m][n], 0, 0, 0);
    }
  }

  // epilogue: bias + fast gelu. C/D layout (m89): col = l&15, row = (l>>4)*4+reg
#pragma unroll
  for (int n = 0; n < 4; ++n) {
    const int col = brow0 + wc * 64 + n * 16 + l15;
    const float bb = biasf[col];
#pragma unroll
    for (int m = 0; m < 4; ++m) {
      const size_t rbase = arow0 + wr * 64 + m * 16 + lhi * 4;
#pragma unroll
      for (int r = 0; r < 4; ++r) {
        const float v = acc[m][n][r] + bb;
        out[(rbase + r) * NDIM + col] = gelu_f(v);
      }
    }
  }
}

// ---------------------------------------------------------------------------
extern "C" void kernel_launch(void* const* d_in, const int* in_sizes, int n_in,
                              void* d_out, int out_size, void* d_ws, size_t ws_size,
                              hipStream_t stream) {
  const float* x     = (const float*)d_in[0];
  const float* gamma = (const float*)d_in[1];
  const float* beta  = (const float*)d_in[2];
  const float* W     = (const float*)d_in[3];
  const float* b     = (const float*)d_in[4];
  float* out = (float*)d_out;

  // ws layout: WT 2MB | h 64MB | partial 64KB | biasf 2KB
  char* p = (char*)d_ws;
  unsigned short* WT = (unsigned short*)p;            p += (size_t)NDIM * KDIM * 2;
  unsigned short* h  = (unsigned short*)p;            p += (size_t)MROWS * KDIM * 2;
  float* partial     = (float*)p;                     p += (size_t)32 * NDIM * 4;
  float* biasf       = (float*)p;

  setup_kernel<<<288, 256, 0, stream>>>(W, gamma, beta, WT, partial);
  kbias2<<<2, 256, 0, stream>>>(b, partial, biasf);
  ln_kernel<<<XROWS / 8, 256, 0, stream>>>(x, h);
  gemm_kernel<<<(MROWS / 128) * 4, 256, 0, stream>>>(h, WT, biasf, out);
}